// Round 5
// baseline (373.971 us; speedup 1.0000x reference)
//
#include <hip/hip_runtime.h>

// Chamfer forward: dist0[i] = min_j ||pc0[i]-pc1[j]||^2 ; out = mean(dist0[dist0<=2])
// N = M = 65536, fp32. VALU-bound brute force.
// m_j = 0.5||c_j||^2 - p.c_j (half-norm in LDS .w); d = max(2*min_m + ||p||^2, 0).
// Points packed in pairs (float2) -> v_pk_fma_f32 (2 fp32 FMA/lane/cyc, the only
// path to the 157 TF fp32 peak). Per point-pair per 2 candidates: 6 pk_fma + 2 min3
// = 2 instr/point*candidate -> VALU floor ~109 us.
// amdgpu_waves_per_eu(4,4): pin occupancy target to the grid's 4 blocks/CU so the
// RA uses ~100 VGPRs instead of chunking the p-loop at 52 (round-4 failure).

typedef float v2f __attribute__((ext_vector_type(2)));

constexpr int TILE  = 1024;   // candidates per LDS tile (float4 = 16 KB)
constexpr int BLOCK = 256;
constexpr int P     = 16;     // points per thread
constexpr int PP    = P / 2;  // packed point pairs
constexpr int S     = 64;     // candidate slices (grid.y)

static __device__ __forceinline__ v2f pk_fma(v2f a, v2f b, v2f c) {
#if __has_builtin(__builtin_elementwise_fma)
  return __builtin_elementwise_fma(a, b, c);
#else
  v2f r; r.x = fmaf(a.x, b.x, c.x); r.y = fmaf(a.y, b.y, c.y); return r;
#endif
}

__global__ __launch_bounds__(BLOCK) __attribute__((amdgpu_waves_per_eu(4, 4)))
void nn_min_kernel(const float* __restrict__ pc0, const float* __restrict__ pc1,
                   unsigned int* __restrict__ bests /* [n0] fp32 bits */) {
  __shared__ float4 s[TILE];

  const int t = threadIdx.x;
  const int pointBase = blockIdx.x * (BLOCK * P);
  const int c0        = blockIdx.y * TILE;

  // stage TILE candidates: 4 candidates/thread via 3 coalesced float4 loads
  {
    const int cbase = 4 * t;
    const float4* g = (const float4*)(pc1 + (size_t)3 * (c0 + cbase));
    const float4 a = g[0], b = g[1], c = g[2];
    s[cbase + 0] = make_float4(a.x, a.y, a.z,
                               0.5f * fmaf(a.x, a.x, fmaf(a.y, a.y, a.z * a.z)));
    s[cbase + 1] = make_float4(a.w, b.x, b.y,
                               0.5f * fmaf(a.w, a.w, fmaf(b.x, b.x, b.y * b.y)));
    s[cbase + 2] = make_float4(b.z, b.w, c.x,
                               0.5f * fmaf(b.z, b.z, fmaf(b.w, b.w, c.x * c.x)));
    s[cbase + 3] = make_float4(c.y, c.z, c.w,
                               0.5f * fmaf(c.y, c.y, fmaf(c.z, c.z, c.w * c.w)));
  }

  // P points, negated, packed as pairs (p=2*pp and p=2*pp+1)
  v2f nx2[PP], ny2[PP], nz2[PP];
  float best[P];
#pragma unroll
  for (int pp = 0; pp < PP; ++pp) {
    const int i0 = pointBase + (2 * pp) * BLOCK + t;   // coalesced per slot
    const int i1 = i0 + BLOCK;
    nx2[pp] = (v2f){-pc0[3 * i0 + 0], -pc0[3 * i1 + 0]};
    ny2[pp] = (v2f){-pc0[3 * i0 + 1], -pc0[3 * i1 + 1]};
    nz2[pp] = (v2f){-pc0[3 * i0 + 2], -pc0[3 * i1 + 2]};
    best[2 * pp] = 3.4e38f;
    best[2 * pp + 1] = 3.4e38f;
  }
  __syncthreads();

  for (int k = 0; k < TILE; k += 2) {
    const float4 ca = s[k];     // wave-uniform addr -> broadcast, conflict-free
    const float4 cb = s[k + 1];
    const v2f cax = (v2f){ca.x, ca.x}, cay = (v2f){ca.y, ca.y};
    const v2f caz = (v2f){ca.z, ca.z}, caw = (v2f){ca.w, ca.w};
    const v2f cbx = (v2f){cb.x, cb.x}, cby = (v2f){cb.y, cb.y};
    const v2f cbz = (v2f){cb.z, cb.z}, cbw = (v2f){cb.w, cb.w};
#pragma unroll
    for (int pp = 0; pp < PP; ++pp) {
      const v2f m0 = pk_fma(nx2[pp], cax, pk_fma(ny2[pp], cay, pk_fma(nz2[pp], caz, caw)));
      const v2f m1 = pk_fma(nx2[pp], cbx, pk_fma(ny2[pp], cby, pk_fma(nz2[pp], cbz, cbw)));
      best[2 * pp]     = fminf(best[2 * pp],     fminf(m0.x, m1.x));  // v_min3_f32
      best[2 * pp + 1] = fminf(best[2 * pp + 1], fminf(m0.y, m1.y));
    }
  }

  // d = max(2m + ||p||^2, 0) >= 0 -> bitwise atomicMin is order-preserving
#pragma unroll
  for (int pp = 0; pp < PP; ++pp) {
    const float pn0 = fmaf(nx2[pp].x, nx2[pp].x,
                      fmaf(ny2[pp].x, ny2[pp].x, nz2[pp].x * nz2[pp].x));
    const float pn1 = fmaf(nx2[pp].y, nx2[pp].y,
                      fmaf(ny2[pp].y, ny2[pp].y, nz2[pp].y * nz2[pp].y));
    const int i0 = pointBase + (2 * pp) * BLOCK + t;
    const int i1 = i0 + BLOCK;
    const float d0 = fmaxf(fmaf(2.0f, best[2 * pp],     pn0), 0.0f);
    const float d1 = fmaxf(fmaf(2.0f, best[2 * pp + 1], pn1), 0.0f);
    atomicMin(&bests[i0], __float_as_uint(d0));
    atomicMin(&bests[i1], __float_as_uint(d1));
  }
}

__global__ __launch_bounds__(BLOCK) void reduce_kernel(
    const unsigned int* __restrict__ bests, int n0,
    float* __restrict__ accum /* [0]=sum, [1]=count */) {
  const int per = n0 / (gridDim.x * BLOCK);   // elements per thread
  float v = 0.f, c = 0.f;
  for (int j = 0; j < per; ++j) {
    const int i = blockIdx.x * (BLOCK * per) + j * BLOCK + threadIdx.x;
    const float d = __uint_as_float(bests[i]);
    if (d <= 2.0f) { v += d; c += 1.0f; }
  }
  for (int off = 32; off > 0; off >>= 1) {
    v += __shfl_down(v, off, 64);
    c += __shfl_down(c, off, 64);
  }
  __shared__ float wsum[BLOCK / 64], wcnt[BLOCK / 64];
  const int wid = threadIdx.x >> 6;
  if ((threadIdx.x & 63) == 0) { wsum[wid] = v; wcnt[wid] = c; }
  __syncthreads();
  if (threadIdx.x == 0) {
    float sS = 0.f, cS = 0.f;
    for (int w = 0; w < BLOCK / 64; ++w) { sS += wsum[w]; cS += wcnt[w]; }
    atomicAdd(&accum[0], sS);
    atomicAdd(&accum[1], cS);
  }
}

__global__ void finalize_kernel(const float* __restrict__ accum,
                                float* __restrict__ out) {
  out[0] = accum[0] / accum[1];
}

extern "C" void kernel_launch(void* const* d_in, const int* in_sizes, int n_in,
                              void* d_out, int out_size, void* d_ws, size_t ws_size,
                              hipStream_t stream) {
  const float* pc0 = (const float*)d_in[0];
  const float* pc1 = (const float*)d_in[1];
  float* out = (float*)d_out;

  const int n0 = in_sizes[0] / 3;   // 65536
  const int n1 = in_sizes[1] / 3;   // 65536
  (void)n1;

  unsigned int* bests = (unsigned int*)d_ws;              // n0 * 4 bytes
  float* accum = (float*)((char*)d_ws + (size_t)n0 * 4);  // 2 floats

  // init: bests = 0x7F7F7F7F (~3.39e38, > any distance), accum = 0
  hipMemsetAsync(bests, 0x7F, (size_t)n0 * 4, stream);
  hipMemsetAsync(accum, 0, 2 * sizeof(float), stream);

  dim3 grid(n0 / (BLOCK * P), S);   // 16 x 64 = 1024 blocks = 4/CU
  nn_min_kernel<<<grid, BLOCK, 0, stream>>>(pc0, pc1, bests);
  reduce_kernel<<<64, BLOCK, 0, stream>>>(bests, n0, accum);
  finalize_kernel<<<1, 1, 0, stream>>>(accum, out);
}